// Round 6
// baseline (1236.743 us; speedup 1.0000x reference)
//
#include <hip/hip_runtime.h>
#include <hip/hip_bf16.h>
#include <cstdint>

typedef short bf16x8 __attribute__((ext_vector_type(8)));
typedef float f32x4 __attribute__((ext_vector_type(4)));

__device__ __forceinline__ unsigned short f2bf(float f) {
  uint32_t u = __float_as_uint(f);
  u += 0x7fffu + ((u >> 16) & 1u);
  return (unsigned short)(u >> 16);
}
__device__ __forceinline__ float bf2f(unsigned short h) {
  return __uint_as_float(((uint32_t)h) << 16);
}

// ---------------- fp32 -> bf16 conversion ----------------
__global__ __launch_bounds__(256) void conv_f32_bf16(const float4* __restrict__ src,
                                                     ushort4* __restrict__ dst, int n4) {
  int i = blockIdx.x * blockDim.x + threadIdx.x;
  int stride = gridDim.x * blockDim.x;
  for (; i < n4; i += stride) {
    float4 v = src[i];
    ushort4 o;
    o.x = f2bf(v.x); o.y = f2bf(v.y); o.z = f2bf(v.z); o.w = f2bf(v.w);
    dst[i] = o;
  }
}

// ---------------- bf16 GEMM, B-resident / barrier-free K-loop ----------------
// C[m,n] = sum_k A[m,k] * B[n,k],  K == 384 fixed.
// Block: 512 threads (8 waves). Block owns one 128-col n-band; B-slice [128][384]
// lives in LDS (98 KiB, chunk-major => conflict-free frag reads, no swizzle needed).
// A-fragments stream directly from global (no LDS, no barriers in the K-loop).
// Each wave computes 32 rows x 128 cols; block m-tile = 256 rows; ML m-tiles per block.

template <int OUT_MODE>   // 0: bf16 out, no bias; 1: fp32 out + bias
__global__ __launch_bounds__(512, 2) void gemm_bres(const unsigned short* __restrict__ A,
                                                    const unsigned short* __restrict__ B,
                                                    void* __restrict__ Cout,
                                                    const float* __restrict__ bias,
                                                    int M, int N, int ML) {
  const int K = 384;                       // 48 16B-chunks per row
  __shared__ unsigned short Bs[48 * 128 * 8];   // chunk-major: Bs[(kc*128 + n)*8 .. +8]

  const int tid  = threadIdx.x;
  const int lane = tid & 63;
  const int wave = tid >> 6;

  // XCD-chunked 1D grid (nwg % 8 == 0), n-band fastest => the 9 (or 3) blocks sharing
  // an A-panel are co-resident on one XCD => A panel L2-hits.
  const int nwg = gridDim.x;
  const int swz = ((blockIdx.x & 7) * (nwg >> 3)) + (blockIdx.x >> 3);
  const int ntn = N >> 7;
  const int jb = swz % ntn;
  const int g  = swz / ntn;
  const int bn0 = jb << 7;

  const unsigned short* Bbase = B + (size_t)bn0 * K;

  // --- one-time B-slice load: global (coalesced 64B segments) -> regs -> LDS ---
  {
    const int br = tid >> 2;               // row 0..127
    const int bj = tid & 3;                // chunk interleave
#pragma unroll
    for (int i = 0; i < 12; ++i) {
      const int cc = bj + 4 * i;           // chunk 0..47
      bf16x8 t = *(const bf16x8*)(Bbase + (size_t)br * K + cc * 8);
      *(bf16x8*)(Bs + (cc * 128 + br) * 8) = t;
    }
  }
  __syncthreads();                         // B resident; no further barriers

  const int fr = lane & 15;
  const int hi = lane >> 4;

  for (int mt = 0; mt < ML; ++mt) {
    const int bm = (g * ML + mt) * 256;
    // wave's A rows: bm + wave*32 + {0,16} + fr ; k-offset hi*8 within each 32-k step
    const unsigned short* Arow = A + (size_t)(bm + wave * 32 + fr) * K + hi * 8;

    f32x4 acc[2][8];
#pragma unroll
    for (int mf = 0; mf < 2; ++mf)
#pragma unroll
      for (int nf = 0; nf < 8; ++nf) {
        f32x4 z = {0.f, 0.f, 0.f, 0.f};
        acc[mf][nf] = z;
      }

#pragma unroll
    for (int ks = 0; ks < 12; ++ks) {
      bf16x8 af0 = *(const bf16x8*)(Arow + ks * 32);
      bf16x8 af1 = *(const bf16x8*)(Arow + (size_t)16 * K + ks * 32);
      bf16x8 bfv[8];
#pragma unroll
      for (int nf = 0; nf < 8; ++nf)
        bfv[nf] = *(const bf16x8*)(Bs + ((ks * 4 + hi) * 128 + nf * 16 + fr) * 8);
#pragma unroll
      for (int nf = 0; nf < 8; ++nf) {
        acc[0][nf] = __builtin_amdgcn_mfma_f32_16x16x32_bf16(af0, bfv[nf], acc[0][nf], 0, 0, 0);
        acc[1][nf] = __builtin_amdgcn_mfma_f32_16x16x32_bf16(af1, bfv[nf], acc[1][nf], 0, 0, 0);
      }
    }

    // C/D layout: col = lane&15, row = (lane>>4)*4 + reg   [guide-verified m89/m91]
    if (OUT_MODE == 1) {
      float* C = (float*)Cout;
#pragma unroll
      for (int mf = 0; mf < 2; ++mf)
#pragma unroll
        for (int nf = 0; nf < 8; ++nf) {
          const int col = bn0 + nf * 16 + fr;
          const float bv = bias[col];
#pragma unroll
          for (int r = 0; r < 4; ++r) {
            const int row = bm + wave * 32 + mf * 16 + hi * 4 + r;
            C[(size_t)row * N + col] = acc[mf][nf][r] + bv;
          }
        }
    } else {
      unsigned short* C = (unsigned short*)Cout;
#pragma unroll
      for (int mf = 0; mf < 2; ++mf)
#pragma unroll
        for (int nf = 0; nf < 8; ++nf) {
          const int col = bn0 + nf * 16 + fr;
#pragma unroll
          for (int r = 0; r < 4; ++r) {
            const int row = bm + wave * 32 + mf * 16 + hi * 4 + r;
            C[(size_t)row * N + col] = f2bf(acc[mf][nf][r]);
          }
        }
    }
  }
}

// ---------------- windowed attention (MFMA, one wave per (b,h,window)) ----------------
#define PADV 24
#define PADP 24
__global__ __launch_bounds__(256) void win_attn(const unsigned short* __restrict__ qkv,
                                                unsigned short* __restrict__ aout) {
  __shared__ unsigned short lds[4][48 * PADV + 16 * PADP];
  const int tid = threadIdx.x;
  const int wave = tid >> 6, lane = tid & 63;
  const int wg = blockIdx.x * 4 + wave;     // ((b*1024 + w)*8 + h)
  const int h = wg & 7;
  const int bw = wg >> 3;
  const int w = bw & 1023, b = bw >> 10;
  const int wy = w >> 5, wx = w & 31;

  unsigned short* Vt = lds[wave];
  unsigned short* P  = lds[wave] + 48 * PADV;

  const int lg = lane >> 4;
  const int lr = lane & 15;

  const int n_lr = (wy * 4 + (lr >> 2)) * 128 + wx * 4 + (lr & 3);
  const size_t rowbase = ((size_t)(b * 16384 + n_lr)) * 1152 + h * 48;

  bf16x8 aq0, bk0;
  bf16x8 aq1 = {0, 0, 0, 0, 0, 0, 0, 0};
  bf16x8 bk1 = {0, 0, 0, 0, 0, 0, 0, 0};
  aq0 = *(const bf16x8*)(qkv + rowbase + lg * 8);
  bk0 = *(const bf16x8*)(qkv + rowbase + 384 + lg * 8);
  if (lg < 2) {
    aq1 = *(const bf16x8*)(qkv + rowbase + 32 + lg * 8);
    bk1 = *(const bf16x8*)(qkv + rowbase + 384 + 32 + lg * 8);
  }

  {
    bf16x8 v = *(const bf16x8*)(qkv + rowbase + 768 + lg * 8);
#pragma unroll
    for (int i = 0; i < 8; ++i) Vt[(lg * 8 + i) * PADV + lr] = (unsigned short)v[i];
    if (lane < 32) {
      bf16x8 v2 = *(const bf16x8*)(qkv + rowbase + 768 + 32 + lg * 8);
#pragma unroll
      for (int i = 0; i < 8; ++i) Vt[((4 + lg) * 8 + i) * PADV + lr] = (unsigned short)v2[i];
    }
  }

  f32x4 s = {0.f, 0.f, 0.f, 0.f};
  s = __builtin_amdgcn_mfma_f32_16x16x32_bf16(aq0, bk0, s, 0, 0, 0);
  s = __builtin_amdgcn_mfma_f32_16x16x32_bf16(aq1, bk1, s, 0, 0, 0);

  const float scale = 0.14433756729740643f;  // 1/sqrt(48)
  float p[4];
#pragma unroll
  for (int r = 0; r < 4; ++r) {
    float x = s[r] * scale;
    float m = x;
    m = fmaxf(m, __shfl_xor(m, 1));
    m = fmaxf(m, __shfl_xor(m, 2));
    m = fmaxf(m, __shfl_xor(m, 4));
    m = fmaxf(m, __shfl_xor(m, 8));
    float e = __expf(x - m);
    float t = e;
    t += __shfl_xor(t, 1);
    t += __shfl_xor(t, 2);
    t += __shfl_xor(t, 4);
    t += __shfl_xor(t, 8);
    p[r] = e / t;
  }
#pragma unroll
  for (int r = 0; r < 4; ++r) P[(lg * 4 + r) * PADP + lr] = f2bf(p[r]);

  __syncthreads();

  bf16x8 ap = {0, 0, 0, 0, 0, 0, 0, 0};
  if (lg < 2) ap = *(const bf16x8*)(P + lr * PADP + lg * 8);

  f32x4 o[3];
#pragma unroll
  for (int c = 0; c < 3; ++c) {
    bf16x8 bv = {0, 0, 0, 0, 0, 0, 0, 0};
    if (lg < 2) bv = *(const bf16x8*)(Vt + (c * 16 + lr) * PADV + lg * 8);
    f32x4 z = {0.f, 0.f, 0.f, 0.f};
    o[c] = __builtin_amdgcn_mfma_f32_16x16x32_bf16(ap, bv, z, 0, 0, 0);
  }

#pragma unroll
  for (int r = 0; r < 4; ++r) {
    const int qi = lg * 4 + r;
    const int nq = (wy * 4 + (qi >> 2)) * 128 + wx * 4 + (qi & 3);
    const size_t obase = ((size_t)(b * 16384 + nq)) * 384 + h * 48;
#pragma unroll
    for (int c = 0; c < 3; ++c)
      aout[obase + c * 16 + lr] = f2bf(o[c][r]);
  }
}

// ---------------- launch ----------------
extern "C" void kernel_launch(void* const* d_in, const int* in_sizes, int n_in,
                              void* d_out, int out_size, void* d_ws, size_t ws_size,
                              hipStream_t stream) {
  const float* x      = (const float*)d_in[0];
  const float* W_qkv  = (const float*)d_in[1];
  const float* W_proj = (const float*)d_in[2];
  const float* b_proj = (const float*)d_in[3];
  float* out = (float*)d_out;

  const int Bb = 8, Nn = 16384, Cc = 384;
  const int M = Bb * Nn;       // 131072
  const int threeC = 3 * Cc;   // 1152

  char* ws = (char*)d_ws;
  unsigned short* qkv_bf  = (unsigned short*)ws;                                   // M*1152 bf16
  unsigned short* xa_bf   = (unsigned short*)(ws + (size_t)M * threeC * 2);        // M*384  bf16
  unsigned short* wqkv_bf = (unsigned short*)(ws + (size_t)M * threeC * 2 + (size_t)M * Cc * 2);
  unsigned short* wproj_bf = wqkv_bf + threeC * Cc;

  conv_f32_bf16<<<2048, 256, 0, stream>>>((const float4*)x, (ushort4*)xa_bf, M * Cc / 4);
  conv_f32_bf16<<<432, 256, 0, stream>>>((const float4*)W_qkv, (ushort4*)wqkv_bf, threeC * Cc / 4);
  conv_f32_bf16<<<144, 256, 0, stream>>>((const float4*)W_proj, (ushort4*)wproj_bf, Cc * Cc / 4);

  const int ML = 2;            // m-tiles (256 rows) per block
  // qkv = x @ W_qkv^T (bf16 out): grid = (512 row-groups) x 9 n-bands = 2304 = 9*256
  gemm_bres<0><<<(M / (256 * ML)) * (threeC / 128), 512, 0, stream>>>(
      xa_bf, wqkv_bf, qkv_bf, nullptr, M, threeC, ML);

  win_attn<<<Bb * 8 * 1024 / 4, 256, 0, stream>>>(qkv_bf, xa_bf);

  // out = attn @ W_proj^T + b (fp32 out): grid = 256 x 3 = 768 = 3*256
  gemm_bres<1><<<(M / (256 * ML)) * (Cc / 128), 512, 0, stream>>>(
      xa_bf, wproj_bf, out, b_proj, M, Cc, ML);
}

// Round 7
// 417.799 us; speedup vs baseline: 2.9601x; 2.9601x over previous
//
#include <hip/hip_runtime.h>
#include <hip/hip_bf16.h>
#include <cstdint>

#define ASPACE(n) __attribute__((address_space(n)))

typedef short bf16x8 __attribute__((ext_vector_type(8)));
typedef float f32x4 __attribute__((ext_vector_type(4)));

__device__ __forceinline__ unsigned short f2bf(float f) {
  uint32_t u = __float_as_uint(f);
  u += 0x7fffu + ((u >> 16) & 1u);
  return (unsigned short)(u >> 16);
}
__device__ __forceinline__ float bf2f(unsigned short h) {
  return __uint_as_float(((uint32_t)h) << 16);
}

// ---------------- fp32 -> bf16 conversion ----------------
__global__ __launch_bounds__(256) void conv_f32_bf16(const float4* __restrict__ src,
                                                     ushort4* __restrict__ dst, int n4) {
  int i = blockIdx.x * blockDim.x + threadIdx.x;
  int stride = gridDim.x * blockDim.x;
  for (; i < n4; i += stride) {
    float4 v = src[i];
    ushort4 o;
    o.x = f2bf(v.x); o.y = f2bf(v.y); o.z = f2bf(v.z); o.w = f2bf(v.w);
    dst[i] = o;
  }
}

// ---------------- bf16 GEMM (B^T input): C[m,n] = sum_k A[m,k]*B[n,k] ----------------
// BM=128, BN=192, BK=32. 256 threads (4 waves as 2x2; per-wave 64x96 output,
// acc[4][6] = 96 VGPR). Double-buffered LDS 40 KiB -> 3 blocks/CU. 2-phase loop
// (r2-proven skeleton). Swizzle chunk ^= (row>>1)&3 on both sides (r4-proven, 0 conflicts).
// All staging/fragment addresses hoisted out of the K-loop (pointer bump only).

__device__ __forceinline__ void gload16(const unsigned short* g, unsigned short* l) {
  __builtin_amdgcn_global_load_lds((const ASPACE(1) void*)g, (ASPACE(3) void*)l, 16, 0, 0);
}

template <int OUT_MODE>   // 0: bf16 out, no bias; 1: fp32 out + bias
__global__ __launch_bounds__(256, 3) void gemm_bt(const unsigned short* __restrict__ A,
                                                  const unsigned short* __restrict__ B,
                                                  void* __restrict__ Cout,
                                                  const float* __restrict__ bias,
                                                  int M, int N, int K) {
  __shared__ unsigned short As[2][128 * 32];   // 16 KiB
  __shared__ unsigned short Bs[2][192 * 32];   // 24 KiB

  const int tid  = threadIdx.x;
  const int lane = tid & 63;
  const int wave = tid >> 6;
  const int wr = wave >> 1;        // 0..1 -> 64-row band
  const int wc = wave & 1;         // 0..1 -> 96-col band

  // 1D grid: XCD-chunked (nwg % 8 == 0), N-tile fastest for A L2-reuse
  const int nwg = gridDim.x;
  const int swz = (blockIdx.x & 7) * (nwg >> 3) + (blockIdx.x >> 3);
  const int ntn = N / 192;
  const int bn0 = (swz % ntn) * 192;
  const int bm0 = (swz / ntn) << 7;

  const unsigned short* Abase = A + (size_t)bm0 * K;
  const unsigned short* Bbase = B + (size_t)bn0 * K;

  // ---- hoisted per-thread staging addresses (chunk c -> row c>>2, phys chunk c&3,
  //      global col-chunk (c&3)^((row>>1)&3); LDS dest base wave-uniform) ----
  // A: chunks tid, tid+256 (512 total).  B: chunks tid, tid+256, tid+512 (768 total).
  const unsigned short* gA[2];
  const unsigned short* gB[3];
  unsigned short* lA[2];
  unsigned short* lB[3];
#pragma unroll
  for (int i = 0; i < 2; ++i) {
    const int c = i * 256 + tid;
    const int r = c >> 2;
    const int gc = (c & 3) ^ ((r >> 1) & 3);
    gA[i] = Abase + (size_t)r * K + gc * 8;
    lA[i] = (unsigned short*)As + (i * 256 + wave * 64) * 8;   // + buf offset later
  }
#pragma unroll
  for (int i = 0; i < 3; ++i) {
    const int c = i * 256 + tid;
    const int r = c >> 2;
    const int gc = (c & 3) ^ ((r >> 1) & 3);
    gB[i] = Bbase + (size_t)r * K + gc * 8;
    lB[i] = (unsigned short*)Bs + (i * 256 + wave * 64) * 8;
  }
  const int abufoff = 128 * 32;   // shorts per A buffer
  const int bbufoff = 192 * 32;

  // ---- hoisted fragment LDS offsets (shorts) ----
  const int fr = lane & 15;
  const int hi = lane >> 4;       // chunk cb
  int afo[4], bfo[6];
#pragma unroll
  for (int m = 0; m < 4; ++m) {
    const int row = wr * 64 + m * 16 + fr;
    afo[m] = row * 32 + ((hi ^ ((row >> 1) & 3)) * 8);
  }
#pragma unroll
  for (int n = 0; n < 6; ++n) {
    const int row = wc * 96 + n * 16 + fr;
    bfo[n] = row * 32 + ((hi ^ ((row >> 1) & 3)) * 8);
  }

  f32x4 acc[4][6];
#pragma unroll
  for (int m = 0; m < 4; ++m)
#pragma unroll
    for (int n = 0; n < 6; ++n) {
      f32x4 z = {0.f, 0.f, 0.f, 0.f};
      acc[m][n] = z;
    }

  const int NT = K >> 5;          // 12 for K=384

  // prologue: stage tile 0 into buf 0
#pragma unroll
  for (int i = 0; i < 2; ++i) gload16(gA[i], lA[i]);
#pragma unroll
  for (int i = 0; i < 3; ++i) gload16(gB[i], lB[i]);
  __syncthreads();

  int cur = 0;
  for (int t = 0; t < NT; ++t) {
    if (t + 1 < NT) {             // stage next tile into buf cur^1 (overlaps compute)
      const int nb = cur ^ 1;
      const int k0 = (t + 1) << 5;
#pragma unroll
      for (int i = 0; i < 2; ++i) gload16(gA[i] + k0, lA[i] + nb * abufoff);
#pragma unroll
      for (int i = 0; i < 3; ++i) gload16(gB[i] + k0, lB[i] + nb * bbufoff);
    }
    // compute current tile
    {
      const unsigned short* Ab = (const unsigned short*)As + cur * abufoff;
      const unsigned short* Bb = (const unsigned short*)Bs + cur * bbufoff;
      bf16x8 af[4], bfv[6];
#pragma unroll
      for (int m = 0; m < 4; ++m) af[m] = *(const bf16x8*)(Ab + afo[m]);
#pragma unroll
      for (int n = 0; n < 6; ++n) bfv[n] = *(const bf16x8*)(Bb + bfo[n]);
#pragma unroll
      for (int m = 0; m < 4; ++m)
#pragma unroll
        for (int n = 0; n < 6; ++n)
          acc[m][n] = __builtin_amdgcn_mfma_f32_16x16x32_bf16(af[m], bfv[n], acc[m][n], 0, 0, 0);
    }
    __syncthreads();              // next tile staged & all reads of buf[cur] done
    cur ^= 1;
  }

  // epilogue: C/D layout col = lane&15, row = (lane>>4)*4 + reg   [guide-verified m89/m91]
  const int rq = hi * 4;
  if (OUT_MODE == 1) {
    float* C = (float*)Cout;
#pragma unroll
    for (int m = 0; m < 4; ++m) {
#pragma unroll
      for (int n = 0; n < 6; ++n) {
        const int col = bn0 + wc * 96 + n * 16 + fr;
        const float bv = bias[col];
#pragma unroll
        for (int r = 0; r < 4; ++r) {
          const int row = bm0 + wr * 64 + m * 16 + rq + r;
          C[(size_t)row * N + col] = acc[m][n][r] + bv;
        }
      }
    }
  } else {
    unsigned short* C = (unsigned short*)Cout;
#pragma unroll
    for (int m = 0; m < 4; ++m) {
#pragma unroll
      for (int n = 0; n < 6; ++n) {
        const int col = bn0 + wc * 96 + n * 16 + fr;
#pragma unroll
        for (int r = 0; r < 4; ++r) {
          const int row = bm0 + wr * 64 + m * 16 + rq + r;
          C[(size_t)row * N + col] = f2bf(acc[m][n][r]);
        }
      }
    }
  }
}

// ---------------- windowed attention (MFMA, one wave per (b,h,window)) ----------------
#define PADV 24
#define PADP 24
__global__ __launch_bounds__(256) void win_attn(const unsigned short* __restrict__ qkv,
                                                unsigned short* __restrict__ aout) {
  __shared__ unsigned short lds[4][48 * PADV + 16 * PADP];
  const int tid = threadIdx.x;
  const int wave = tid >> 6, lane = tid & 63;
  const int wg = blockIdx.x * 4 + wave;     // ((b*1024 + w)*8 + h)
  const int h = wg & 7;
  const int bw = wg >> 3;
  const int w = bw & 1023, b = bw >> 10;
  const int wy = w >> 5, wx = w & 31;

  unsigned short* Vt = lds[wave];
  unsigned short* P  = lds[wave] + 48 * PADV;

  const int lg = lane >> 4;
  const int lr = lane & 15;

  const int n_lr = (wy * 4 + (lr >> 2)) * 128 + wx * 4 + (lr & 3);
  const size_t rowbase = ((size_t)(b * 16384 + n_lr)) * 1152 + h * 48;

  bf16x8 aq0, bk0;
  bf16x8 aq1 = {0, 0, 0, 0, 0, 0, 0, 0};
  bf16x8 bk1 = {0, 0, 0, 0, 0, 0, 0, 0};
  aq0 = *(const bf16x8*)(qkv + rowbase + lg * 8);
  bk0 = *(const bf16x8*)(qkv + rowbase + 384 + lg * 8);
  if (lg < 2) {
    aq1 = *(const bf16x8*)(qkv + rowbase + 32 + lg * 8);
    bk1 = *(const bf16x8*)(qkv + rowbase + 384 + 32 + lg * 8);
  }

  {
    bf16x8 v = *(const bf16x8*)(qkv + rowbase + 768 + lg * 8);
#pragma unroll
    for (int i = 0; i < 8; ++i) Vt[(lg * 8 + i) * PADV + lr] = (unsigned short)v[i];
    if (lane < 32) {
      bf16x8 v2 = *(const bf16x8*)(qkv + rowbase + 768 + 32 + lg * 8);
#pragma unroll
      for (int i = 0; i < 8; ++i) Vt[((4 + lg) * 8 + i) * PADV + lr] = (unsigned short)v2[i];
    }
  }

  f32x4 s = {0.f, 0.f, 0.f, 0.f};
  s = __builtin_amdgcn_mfma_f32_16x16x32_bf16(aq0, bk0, s, 0, 0, 0);
  s = __builtin_amdgcn_mfma_f32_16x16x32_bf16(aq1, bk1, s, 0, 0, 0);

  const float scale = 0.14433756729740643f;  // 1/sqrt(48)
  float p[4];
#pragma unroll
  for (int r = 0; r < 4; ++r) {
    float x = s[r] * scale;
    float m = x;
    m = fmaxf(m, __shfl_xor(m, 1));
    m = fmaxf(m, __shfl_xor(m, 2));
    m = fmaxf(m, __shfl_xor(m, 4));
    m = fmaxf(m, __shfl_xor(m, 8));
    float e = __expf(x - m);
    float t = e;
    t += __shfl_xor(t, 1);
    t += __shfl_xor(t, 2);
    t += __shfl_xor(t, 4);
    t += __shfl_xor(t, 8);
    p[r] = e / t;
  }
#pragma unroll
  for (int r = 0; r < 4; ++r) P[(lg * 4 + r) * PADP + lr] = f2bf(p[r]);

  __syncthreads();

  bf16x8 ap = {0, 0, 0, 0, 0, 0, 0, 0};
  if (lg < 2) ap = *(const bf16x8*)(P + lr * PADP + lg * 8);

  f32x4 o[3];
#pragma unroll
  for (int c = 0; c < 3; ++c) {
    bf16x8 bv = {0, 0, 0, 0, 0, 0, 0, 0};
    if (lg < 2) bv = *(const bf16x8*)(Vt + (c * 16 + lr) * PADV + lg * 8);
    f32x4 z = {0.f, 0.f, 0.f, 0.f};
    o[c] = __builtin_amdgcn_mfma_f32_16x16x32_bf16(ap, bv, z, 0, 0, 0);
  }

#pragma unroll
  for (int r = 0; r < 4; ++r) {
    const int qi = lg * 4 + r;
    const int nq = (wy * 4 + (qi >> 2)) * 128 + wx * 4 + (qi & 3);
    const size_t obase = ((size_t)(b * 16384 + nq)) * 384 + h * 48;
#pragma unroll
    for (int c = 0; c < 3; ++c)
      aout[obase + c * 16 + lr] = f2bf(o[c][r]);
  }
}

// ---------------- launch ----------------
extern "C" void kernel_launch(void* const* d_in, const int* in_sizes, int n_in,
                              void* d_out, int out_size, void* d_ws, size_t ws_size,
                              hipStream_t stream) {
  const float* x      = (const float*)d_in[0];
  const float* W_qkv  = (const float*)d_in[1];
  const float* W_proj = (const float*)d_in[2];
  const float* b_proj = (const float*)d_in[3];
  float* out = (float*)d_out;

  const int Bb = 8, Nn = 16384, Cc = 384;
  const int M = Bb * Nn;       // 131072
  const int threeC = 3 * Cc;   // 1152

  char* ws = (char*)d_ws;
  unsigned short* qkv_bf  = (unsigned short*)ws;                                   // M*1152 bf16
  unsigned short* xa_bf   = (unsigned short*)(ws + (size_t)M * threeC * 2);        // M*384  bf16
  unsigned short* wqkv_bf = (unsigned short*)(ws + (size_t)M * threeC * 2 + (size_t)M * Cc * 2);
  unsigned short* wproj_bf = wqkv_bf + threeC * Cc;

  conv_f32_bf16<<<2048, 256, 0, stream>>>((const float4*)x, (ushort4*)xa_bf, M * Cc / 4);
  conv_f32_bf16<<<432, 256, 0, stream>>>((const float4*)W_qkv, (ushort4*)wqkv_bf, threeC * Cc / 4);
  conv_f32_bf16<<<144, 256, 0, stream>>>((const float4*)W_proj, (ushort4*)wproj_bf, Cc * Cc / 4);

  // qkv = x @ W_qkv^T (bf16 out): grid = 1024 m-tiles x 6 n-bands = 6144 (%8==0)
  gemm_bt<0><<<(M / 128) * (threeC / 192), 256, 0, stream>>>(xa_bf, wqkv_bf, qkv_bf, nullptr,
                                                             M, threeC, Cc);

  win_attn<<<Bb * 8 * 1024 / 4, 256, 0, stream>>>(qkv_bf, xa_bf);

  // out = attn @ W_proj^T + b (fp32 out): grid = 1024 x 2 = 2048 (%8==0)
  gemm_bt<1><<<(M / 128) * (Cc / 192), 256, 0, stream>>>(xa_bf, wproj_bf, out, b_proj,
                                                         M, Cc, Cc);
}